// Round 18
// baseline (293.957 us; speedup 1.0000x reference)
//
#include <hip/hip_runtime.h>
#include <hip/hip_bf16.h>

// ---------------------------------------------------------------------------
// PAWSA fused windowed attention, MI355X / gfx950 — round 18: 2 windows/block.
// Inputs f32, output f32 (out0 [8192,49,96], out1 v_hw [8,3,96] at elem
// offset 38,535,168). Grid 4096 x 256; each block processes windows
// {2*bid, 2*bid+1} (never straddles a batch boundary).
// = R17 per-window code, state x2 for per-wave ILP:
//   - LDS 79,840 B (2 x R17 layout) -> 2 blocks/CU; __launch_bounds__(256,2)
//     -> 256-VGPR budget (min-waves/EU and min-blocks semantics agree here).
//   - QKV weight fragments loaded ONCE per tile, used for both windows.
//   - Two independent attention chains per wave -> stalls of A filled by B.
//   - All per-window math identical to R17 (verified absmax 4.88e-4).
// Spill tripwire: FETCH/WRITE balloon. Occupancy will READ ~25% (8 waves/CU)
// by design — stream count/CU unchanged (16), ILP doubled.
// ---------------------------------------------------------------------------

typedef __bf16 bf16x8 __attribute__((ext_vector_type(8)));
typedef float  f32x4  __attribute__((ext_vector_type(4)));
typedef short  s16x4  __attribute__((ext_vector_type(4)));
typedef unsigned short u16x4 __attribute__((ext_vector_type(4)));
using bf16 = __hip_bfloat16;

#define SCALE 0.17677669529663687f   // 32^-0.5

// LDS partition per window (units: 16-bit elements); window u at +u*19960
#define LDS_XQ    0       // [49][100] q (rows<49) -> O
#define LDS_K     4900    // [52][100] k
#define LDS_P     10100   // [49][68]  P (bf16 probs, per head)
#define LDS_VT    13432   // [96][68]  v^T: vt[h*32+d][token]
#define WIN_SZ    19960
#define LDS_TOT   39920   // shorts -> 79,840 B

static __device__ inline float s2f(unsigned short s) {
    unsigned int u = ((unsigned int)s) << 16;
    float f;
    __builtin_memcpy(&f, &u, 4);
    return f;
}
static __device__ inline short f2s(float f) {   // hardware cvt
    __bf16 h = (__bf16)f;
    short s;
    __builtin_memcpy(&s, &h, 2);
    return s;
}
static __device__ inline bf16x8 ldw8(const float* p) {   // f32 -> bf16 fragment
    f32x4 a = *reinterpret_cast<const f32x4*>(p);
    f32x4 b = *reinterpret_cast<const f32x4*>(p + 4);
    bf16x8 r;
    #pragma unroll
    for (int i = 0; i < 4; ++i) {
        r[i]     = (__bf16)a[i];
        r[i + 4] = (__bf16)b[i];
    }
    return r;
}

// ---- prep: bf16 weights (blocks 0-143) + gathered bias table (block 144) ----
// ws layout (bf16 elems): [0,27648) qkv_w | [27648,36864) proj_w |
//                         [36864, +12288) biasg as ushort4[12][256]
__global__ __launch_bounds__(256)
void pawsa_prep(const float* __restrict__ qkv_w, const float* __restrict__ proj_w,
                const float* __restrict__ bias_table, bf16* __restrict__ ws)
{
    int blk = blockIdx.x, t = threadIdx.x;
    if (blk < 144) {
        int i = blk * 256 + t;
        if (i < 27648)      ws[i] = __float2bfloat16(qkv_w[i]);
        else if (i < 36864) ws[i] = __float2bfloat16(proj_w[i - 27648]);
        return;
    }
    // biasg[(h*4+nt)*256 + t] = {bias[idx(n=wid*16+lg*4+j, c=nt*16+lr)][h]}
    int lane = t & 63, wid = t >> 6;
    int lr = lane & 15, lg = lane >> 4;
    u16x4* bg = reinterpret_cast<u16x4*>(ws + 36864);
    for (int h = 0; h < 3; ++h) {
        for (int nt = 0; nt < 4; ++nt) {
            int c = nt * 16 + lr;
            u16x4 v4;
            for (int j = 0; j < 4; ++j) {
                int n = wid * 16 + lg * 4 + j;
                int idx = 171;
                if (c < 49) {
                    idx = (n / 7 - c / 7 + 6) * 13 + ((n % 7) - (c % 7) + 6);
                    if (idx > 171 || idx < 0) idx = 171;   // garbage rows n>=49
                } else if (c < 52) {
                    idx = 169 + (c - 49);
                }
                v4[j] = (unsigned short)f2s(bias_table[idx * 3 + h]);
            }
            bg[(h * 4 + nt) * 256 + t] = v4;
        }
    }
}

__global__ __launch_bounds__(256, 2)
void pawsa_main(const float* __restrict__ x, const float* __restrict__ mask,
                const float* __restrict__ uk, const float* __restrict__ fg,
                const float* __restrict__ bg,
                const bf16* __restrict__ wq,    // bf16 qkv_w (d_ws)
                const float* __restrict__ qkv_b,
                const bf16* __restrict__ wp,    // bf16 proj_w (d_ws)
                const float* __restrict__ proj_b,
                const u16x4* __restrict__ biasg, // gathered bias (d_ws)
                float* __restrict__ out)
{
    __shared__ short smem[LDS_TOT];

    const int tid  = threadIdx.x;
    const int w0   = blockIdx.x * 2;   // first of the window pair
    const int lane = tid & 63;
    const int wid  = tid >> 6;         // wave id 0..3
    const int lr   = lane & 15;        // row/col within 16-tile
    const int lg   = lane >> 4;        // k-group 0..3

    // ---- X tiles (both windows) -> registers directly ----
    bf16x8 af[2][3][4];
    #pragma unroll
    for (int u = 0; u < 2; ++u) {
        int w = w0 + u, b = w >> 10;
        #pragma unroll
        for (int mt = 0; mt < 4; ++mt) {
            int n = mt * 16 + lr;
            #pragma unroll
            for (int ks = 0; ks < 3; ++ks) {
                bf16x8 a = (bf16x8)0;
                if (n < 49) {
                    a = ldw8(x + ((size_t)w * 49 + n) * 96 + ks * 32 + lg * 8);
                } else if (n < 52) {
                    const float* pr = (n == 49) ? uk : (n == 50) ? fg : bg;
                    a = ldw8(pr + b * 96 + ks * 32 + lg * 8);
                }
                af[u][ks][mt] = a;
            }
        }
    }

    // ---- QKV GEMM, swapped operands, weights shared across both windows ----
    const int nt0 = (wid < 3) ? wid * 5 : 13;   // tiles 0-4,5-9,10-14,13-17
    #pragma unroll
    for (int i = 0; i < 5; ++i) {
        int nt = nt0 + i;
        bf16x8 bw0 = *reinterpret_cast<const bf16x8*>(wq + (nt * 16 + lr) * 96 +  0 + lg * 8);
        bf16x8 bw1 = *reinterpret_cast<const bf16x8*>(wq + (nt * 16 + lr) * 96 + 32 + lg * 8);
        bf16x8 bw2 = *reinterpret_cast<const bf16x8*>(wq + (nt * 16 + lr) * 96 + 64 + lg * 8);
        f32x4 qb4 = *reinterpret_cast<const f32x4*>(qkv_b + nt * 16 + lg * 4);
        int s = nt / 6;                       // 0=q 1=k 2=v (tile-uniform)
        int remBase = (nt - s * 6) * 16 + lg * 4;
        #pragma unroll
        for (int u = 0; u < 2; ++u) {
            const int WB = u * WIN_SZ;
            f32x4 acc[4] = {(f32x4)0.f, (f32x4)0.f, (f32x4)0.f, (f32x4)0.f};
            #pragma unroll
            for (int mt = 0; mt < 4; ++mt) {
                acc[mt] = __builtin_amdgcn_mfma_f32_16x16x32_bf16(bw0, af[u][0][mt], acc[mt], 0, 0, 0);
                acc[mt] = __builtin_amdgcn_mfma_f32_16x16x32_bf16(bw1, af[u][1][mt], acc[mt], 0, 0, 0);
                acc[mt] = __builtin_amdgcn_mfma_f32_16x16x32_bf16(bw2, af[u][2][mt], acc[mt], 0, 0, 0);
            }
            #pragma unroll
            for (int mt = 0; mt < 4; ++mt) {
                int n = mt * 16 + lr;             // token (uniform over j)
                if (s == 2) {                     // v^T: 4 channel-rows, col n
                    #pragma unroll
                    for (int j = 0; j < 4; ++j)
                        smem[WB + LDS_VT + (remBase + j) * 68 + n] = f2s(acc[mt][j] + qb4[j]);
                } else {
                    s16x4 pk;
                    #pragma unroll
                    for (int j = 0; j < 4; ++j) pk[j] = f2s(acc[mt][j] + qb4[j]);
                    if (s == 0) { if (n < 49) *reinterpret_cast<s16x4*>(
                                      &smem[WB + LDS_XQ + n * 100 + remBase]) = pk; }
                    else        { if (n < 52) *reinterpret_cast<s16x4*>(
                                      &smem[WB + LDS_K  + n * 100 + remBase]) = pk; }
                }
            }
        }
    }

    // ---- mask + gathered-bias loads (af dead; hidden under barrier wait) ----
    float mk[2][4][4];
    #pragma unroll
    for (int u = 0; u < 2; ++u) {
        int wiu = (w0 + u) & 1023;
        #pragma unroll
        for (int nt = 0; nt < 4; ++nt) {
            int c = nt * 16 + lr;
            #pragma unroll
            for (int j = 0; j < 4; ++j) {
                int n = wid * 16 + lg * 4 + j;
                float m = 0.f;
                if (c < 49 && n < 49)
                    m = mask[(size_t)wiu * 2401 + n * 49 + c];
                mk[u][nt][j] = m;
            }
        }
    }
    u16x4 bgv[12];
    #pragma unroll
    for (int i = 0; i < 12; ++i) bgv[i] = biasg[i * 256 + tid];

    __syncthreads();
    // From here: K, VT read-only; XQ/P rows wave-private (per window half).

    // ---- per-head attention, both windows (independent chains per wave) ----
    #pragma unroll
    for (int h = 0; h < 3; ++h) {
        #pragma unroll
        for (int u = 0; u < 2; ++u) {
            const int WB = u * WIN_SZ;
            bf16x8 aq = *reinterpret_cast<const bf16x8*>(
                &smem[WB + LDS_XQ + (wid * 16 + lr) * 100 + h * 32 + lg * 8]);
            f32x4 sacc[4];
            #pragma unroll
            for (int nt = 0; nt < 4; ++nt) {
                bf16x8 bk = *reinterpret_cast<const bf16x8*>(
                    &smem[WB + LDS_K + (nt * 16 + lr) * 100 + h * 32 + lg * 8]);
                sacc[nt] = __builtin_amdgcn_mfma_f32_16x16x32_bf16(aq, bk, (f32x4)0.f, 0, 0, 0);
            }
            float lgt[4][4];
            #pragma unroll
            for (int nt = 0; nt < 4; ++nt) {
                int c = nt * 16 + lr;
                u16x4 bgq = bgv[h * 4 + nt];
                #pragma unroll
                for (int j = 0; j < 4; ++j) {
                    float v = -1e30f;
                    if (c < 52)
                        v = sacc[nt][j] * SCALE + s2f(bgq[j]) + mk[u][nt][j];
                    lgt[nt][j] = v;
                }
            }
            float pr[4][4];
            #pragma unroll
            for (int j = 0; j < 4; ++j) {
                float m = fmaxf(fmaxf(lgt[0][j], lgt[1][j]), fmaxf(lgt[2][j], lgt[3][j]));
                m = fmaxf(m, __shfl_xor(m, 1));
                m = fmaxf(m, __shfl_xor(m, 2));
                m = fmaxf(m, __shfl_xor(m, 4));
                m = fmaxf(m, __shfl_xor(m, 8));
                float sum = 0.f;
                #pragma unroll
                for (int nt = 0; nt < 4; ++nt) {
                    pr[nt][j] = __expf(lgt[nt][j] - m);
                    sum += pr[nt][j];
                }
                sum += __shfl_xor(sum, 1);
                sum += __shfl_xor(sum, 2);
                sum += __shfl_xor(sum, 4);
                sum += __shfl_xor(sum, 8);
                float inv = 1.0f / sum;
                #pragma unroll
                for (int nt = 0; nt < 4; ++nt) pr[nt][j] *= inv;
            }
            #pragma unroll
            for (int nt = 0; nt < 4; ++nt)
                #pragma unroll
                for (int j = 0; j < 4; ++j) {
                    int prow = wid * 16 + lg * 4 + j;
                    if (prow < 49)
                        smem[WB + LDS_P + prow * 68 + nt * 16 + lr] = f2s(pr[nt][j]);
                }

            // O_h = P @ V (K=52 padded to 64; P cols 52-63 exact zeros)
            f32x4 ov[2] = {(f32x4)0.f, (f32x4)0.f};
            #pragma unroll
            for (int ks = 0; ks < 2; ++ks) {
                bf16x8 ap = *reinterpret_cast<const bf16x8*>(
                    &smem[WB + LDS_P + (wid * 16 + lr) * 68 + ks * 32 + lg * 8]);
                #pragma unroll
                for (int nt2 = 0; nt2 < 2; ++nt2) {
                    bf16x8 bv = *reinterpret_cast<const bf16x8*>(
                        &smem[WB + LDS_VT + (h * 32 + nt2 * 16 + lr) * 68 + ks * 32 + lg * 8]);
                    ov[nt2] = __builtin_amdgcn_mfma_f32_16x16x32_bf16(ap, bv, ov[nt2], 0, 0, 0);
                }
            }
            #pragma unroll
            for (int nt2 = 0; nt2 < 2; ++nt2)
                #pragma unroll
                for (int j = 0; j < 4; ++j) {
                    int orow = wid * 16 + lg * 4 + j;
                    if (orow < 49)
                        smem[WB + LDS_XQ + orow * 100 + h * 32 + nt2 * 16 + lr]
                            = f2s(ov[nt2][j]);
                }
        }
    }

    // ---- projection, weights shared across both windows ----
    f32x4 po[2][6];
    #pragma unroll
    for (int u = 0; u < 2; ++u)
        #pragma unroll
        for (int nt = 0; nt < 6; ++nt) po[u][nt] = (f32x4)0.f;
    #pragma unroll
    for (int ks = 0; ks < 3; ++ks) {
        bf16x8 a0 = *reinterpret_cast<const bf16x8*>(
            &smem[0 * WIN_SZ + LDS_XQ + (wid * 16 + lr) * 100 + ks * 32 + lg * 8]);
        bf16x8 a1 = *reinterpret_cast<const bf16x8*>(
            &smem[1 * WIN_SZ + LDS_XQ + (wid * 16 + lr) * 100 + ks * 32 + lg * 8]);
        #pragma unroll
        for (int nt = 0; nt < 6; ++nt) {
            bf16x8 bp = *reinterpret_cast<const bf16x8*>(
                wp + (nt * 16 + lr) * 96 + ks * 32 + lg * 8);
            po[0][nt] = __builtin_amdgcn_mfma_f32_16x16x32_bf16(a0, bp, po[0][nt], 0, 0, 0);
            po[1][nt] = __builtin_amdgcn_mfma_f32_16x16x32_bf16(a1, bp, po[1][nt], 0, 0, 0);
        }
    }
    #pragma unroll
    for (int nt = 0; nt < 6; ++nt) {
        float pb = proj_b[nt * 16 + lr];
        #pragma unroll
        for (int u = 0; u < 2; ++u) {
            size_t wbase = (size_t)(w0 + u) * 49;
            #pragma unroll
            for (int j = 0; j < 4; ++j) {
                int n = wid * 16 + lg * 4 + j;
                if (n < 49)
                    out[(wbase + n) * 96 + nt * 16 + lr] = po[u][nt][j] + pb;
            }
        }
    }
}

// ---------------- prior highway: v_hw = proj(v(qkv(prior))) ----------------
__global__ __launch_bounds__(128)
void pawsa_prior(const float* __restrict__ uk, const float* __restrict__ fg,
                 const float* __restrict__ bg,
                 const float* __restrict__ qkv_w, const float* __restrict__ qkv_b,
                 const float* __restrict__ proj_w, const float* __restrict__ proj_b,
                 float* __restrict__ out_vhw)
{
    int blk = blockIdx.x;             // 24 = 8 batches * 3 priors
    int b = blk / 3, p = blk % 3;
    int t = threadIdx.x;
    __shared__ float prr[96], vf[96];
    const float* src = (p == 0) ? uk : (p == 1) ? fg : bg;
    if (t < 96) prr[t] = src[b * 96 + t];
    __syncthreads();
    if (t < 96) {
        float acc = qkv_b[192 + t];
        for (int k = 0; k < 96; ++k)
            acc += prr[k] * qkv_w[(192 + t) * 96 + k];
        vf[t] = acc;
    }
    __syncthreads();
    if (t < 96) {
        float acc = proj_b[t];
        for (int c = 0; c < 96; ++c)
            acc += vf[c] * proj_w[t * 96 + c];
        out_vhw[(b * 3 + p) * 96 + t] = acc;
    }
}

extern "C" void kernel_launch(void* const* d_in, const int* in_sizes, int n_in,
                              void* d_out, int out_size, void* d_ws, size_t ws_size,
                              hipStream_t stream) {
    const float* x          = (const float*)d_in[0];
    const float* mask       = (const float*)d_in[1];
    const float* uk         = (const float*)d_in[2];
    const float* fg         = (const float*)d_in[3];
    const float* bg         = (const float*)d_in[4];
    const float* qkv_w      = (const float*)d_in[5];
    const float* qkv_b      = (const float*)d_in[6];
    const float* proj_w     = (const float*)d_in[7];
    const float* proj_b     = (const float*)d_in[8];
    const float* bias_table = (const float*)d_in[9];
    float* out = (float*)d_out;
    bf16* ws   = (bf16*)d_ws;

    pawsa_prep<<<145, 256, 0, stream>>>(qkv_w, proj_w, bias_table, ws);
    pawsa_prior<<<24, 128, 0, stream>>>(uk, fg, bg, qkv_w, qkv_b, proj_w, proj_b,
                                        out + (size_t)8192 * 49 * 96);
    pawsa_main<<<4096, 256, 0, stream>>>(x, mask, uk, fg, bg,
                                         ws, qkv_b, ws + 27648, proj_b,
                                         (const u16x4*)(ws + 36864), out);
}

// Round 19
// 223.927 us; speedup vs baseline: 1.3127x; 1.3127x over previous
//
#include <hip/hip_runtime.h>
#include <hip/hip_bf16.h>

// ---------------------------------------------------------------------------
// PAWSA fused windowed attention, MI355X / gfx950 — round 19.
// Inputs f32, output f32 (out0 [8192,49,96], out1 v_hw [8,3,96] at elem
// offset 38,535,168). One block per window (8192 x 256), bf16 MFMA 16x16x32.
// = R17 (234.7us best: XCD swizzle, swapped QKV, biasg prefetch, 0 conflicts)
//   + swapped PROJECTION: mfma(A=W,B=O) -> D[ch][tok]; epilogue = 6x
//     global_store_dwordx4 (was 24 predicated scalar stores), bias via f32x4.
//     Fragment reads are IDENTICAL to R17 (index algebra verified).
//   + pawsa_prior merged into pawsa_prep (blocks 145-168) — one launch fewer.
// Occupancy map (R12/R14/R17/R18): 16 waves/CU in 4-wave blocks is optimal;
// LDS 39,920 B -> 4 blocks/CU.
// ---------------------------------------------------------------------------

typedef __bf16 bf16x8 __attribute__((ext_vector_type(8)));
typedef float  f32x4  __attribute__((ext_vector_type(4)));
typedef short  s16x4  __attribute__((ext_vector_type(4)));
typedef unsigned short u16x4 __attribute__((ext_vector_type(4)));
using bf16 = __hip_bfloat16;

#define SCALE 0.17677669529663687f   // 32^-0.5

// LDS partition (units: 16-bit elements) — 19,960 shorts = 39,920 B
#define LDS_XQ    0       // [49][100] q (rows<49) -> O
#define LDS_K     4900    // [52][100] k
#define LDS_P     10100   // [49][68]  P (bf16 probs, per head)
#define LDS_VT    13432   // [96][68]  v^T: vt[h*32+d][token]
#define LDS_TOT   19960

static __device__ inline float s2f(unsigned short s) {
    unsigned int u = ((unsigned int)s) << 16;
    float f;
    __builtin_memcpy(&f, &u, 4);
    return f;
}
static __device__ inline short f2s(float f) {   // hardware cvt
    __bf16 h = (__bf16)f;
    short s;
    __builtin_memcpy(&s, &h, 2);
    return s;
}
static __device__ inline bf16x8 ldw8(const float* p) {   // f32 -> bf16 fragment
    f32x4 a = *reinterpret_cast<const f32x4*>(p);
    f32x4 b = *reinterpret_cast<const f32x4*>(p + 4);
    bf16x8 r;
    #pragma unroll
    for (int i = 0; i < 4; ++i) {
        r[i]     = (__bf16)a[i];
        r[i + 4] = (__bf16)b[i];
    }
    return r;
}

// ---- prep: bf16 weights (blocks 0-143) + gathered bias (144) + prior
//      highway (blocks 145-168). ws: [0,27648) qkv_w | [27648,36864) proj_w |
//      [36864,+12288) biasg as ushort4[12][256].
__global__ __launch_bounds__(256)
void pawsa_prep(const float* __restrict__ qkv_w, const float* __restrict__ proj_w,
                const float* __restrict__ bias_table,
                const float* __restrict__ uk, const float* __restrict__ fg,
                const float* __restrict__ bg,
                const float* __restrict__ qkv_b, const float* __restrict__ proj_b,
                bf16* __restrict__ ws, float* __restrict__ out_vhw)
{
    int blk = blockIdx.x, t = threadIdx.x;
    if (blk < 144) {
        int i = blk * 256 + t;
        if (i < 27648)      ws[i] = __float2bfloat16(qkv_w[i]);
        else if (i < 36864) ws[i] = __float2bfloat16(proj_w[i - 27648]);
        return;
    }
    if (blk == 144) {
        // biasg[(h*4+nt)*256 + t] = {bias[idx(n=wid*16+lg*4+j, c=nt*16+lr)][h]}
        int lane = t & 63, wid = t >> 6;
        int lr = lane & 15, lg = lane >> 4;
        u16x4* bg4 = reinterpret_cast<u16x4*>(ws + 36864);
        for (int h = 0; h < 3; ++h) {
            for (int nt = 0; nt < 4; ++nt) {
                int c = nt * 16 + lr;
                u16x4 v4;
                for (int j = 0; j < 4; ++j) {
                    int n = wid * 16 + lg * 4 + j;
                    int idx = 171;
                    if (c < 49) {
                        idx = (n / 7 - c / 7 + 6) * 13 + ((n % 7) - (c % 7) + 6);
                        if (idx > 171 || idx < 0) idx = 171;   // garbage rows n>=49
                    } else if (c < 52) {
                        idx = 169 + (c - 49);
                    }
                    v4[j] = (unsigned short)f2s(bias_table[idx * 3 + h]);
                }
                bg4[(h * 4 + nt) * 256 + t] = v4;
            }
        }
        return;
    }
    // blocks 145-168: prior highway v_hw = proj(v(qkv(prior)))
    int pi = blk - 145;               // 0..23
    int b = pi / 3, p = pi % 3;
    __shared__ float prr[96], vf[96];
    const float* src = (p == 0) ? uk : (p == 1) ? fg : bg;
    if (t < 96) prr[t] = src[b * 96 + t];
    __syncthreads();
    if (t < 96) {
        float acc = qkv_b[192 + t];
        for (int k = 0; k < 96; ++k)
            acc += prr[k] * qkv_w[(192 + t) * 96 + k];
        vf[t] = acc;
    }
    __syncthreads();
    if (t < 96) {
        float acc = proj_b[t];
        for (int c = 0; c < 96; ++c)
            acc += vf[c] * proj_w[t * 96 + c];
        out_vhw[(b * 3 + p) * 96 + t] = acc;
    }
}

__global__ __launch_bounds__(256, 4)
void pawsa_main(const float* __restrict__ x, const float* __restrict__ mask,
                const float* __restrict__ uk, const float* __restrict__ fg,
                const float* __restrict__ bg,
                const bf16* __restrict__ wq,    // bf16 qkv_w (d_ws)
                const float* __restrict__ qkv_b,
                const bf16* __restrict__ wp,    // bf16 proj_w (d_ws)
                const float* __restrict__ proj_b,
                const u16x4* __restrict__ biasg, // gathered bias (d_ws)
                float* __restrict__ out)
{
    __shared__ short smem[LDS_TOT];

    const int tid  = threadIdx.x;
    // XCD-aware swizzle: XCD x owns wi in [x*128,(x+1)*128) for all 8 batches
    const int bid  = blockIdx.x;
    const int xcd  = bid & 7;
    const int slot = bid >> 3;
    const int wi   = xcd * 128 + (slot & 127);
    const int b    = slot >> 7;
    const int w    = b * 1024 + wi;

    const int lane = tid & 63;
    const int wid  = tid >> 6;         // wave id 0..3
    const int lr   = lane & 15;        // row/col within 16-tile
    const int lg   = lane >> 4;        // k-group 0..3

    // ---- X tile -> registers directly (rows<49 x, 49-51 priors, >=52 zero) --
    bf16x8 af[3][4];
    #pragma unroll
    for (int mt = 0; mt < 4; ++mt) {
        int n = mt * 16 + lr;
        #pragma unroll
        for (int ks = 0; ks < 3; ++ks) {
            bf16x8 a = (bf16x8)0;
            if (n < 49) {
                a = ldw8(x + ((size_t)w * 49 + n) * 96 + ks * 32 + lg * 8);
            } else if (n < 52) {
                const float* pr = (n == 49) ? uk : (n == 50) ? fg : bg;
                a = ldw8(pr + b * 96 + ks * 32 + lg * 8);
            }
            af[ks][mt] = a;
        }
    }

    // ---- QKV GEMM, swapped operands: D[channel][token] ----
    const int nt0 = (wid < 3) ? wid * 5 : 13;   // tiles 0-4,5-9,10-14,13-17
    #pragma unroll
    for (int i = 0; i < 5; ++i) {
        int nt = nt0 + i;
        bf16x8 bw0 = *reinterpret_cast<const bf16x8*>(wq + (nt * 16 + lr) * 96 +  0 + lg * 8);
        bf16x8 bw1 = *reinterpret_cast<const bf16x8*>(wq + (nt * 16 + lr) * 96 + 32 + lg * 8);
        bf16x8 bw2 = *reinterpret_cast<const bf16x8*>(wq + (nt * 16 + lr) * 96 + 64 + lg * 8);
        f32x4 qb4 = *reinterpret_cast<const f32x4*>(qkv_b + nt * 16 + lg * 4);
        f32x4 acc[4] = {(f32x4)0.f, (f32x4)0.f, (f32x4)0.f, (f32x4)0.f};
        #pragma unroll
        for (int mt = 0; mt < 4; ++mt) {
            acc[mt] = __builtin_amdgcn_mfma_f32_16x16x32_bf16(bw0, af[0][mt], acc[mt], 0, 0, 0);
            acc[mt] = __builtin_amdgcn_mfma_f32_16x16x32_bf16(bw1, af[1][mt], acc[mt], 0, 0, 0);
            acc[mt] = __builtin_amdgcn_mfma_f32_16x16x32_bf16(bw2, af[2][mt], acc[mt], 0, 0, 0);
        }
        int s = nt / 6;                       // 0=q 1=k 2=v (tile-uniform)
        int remBase = (nt - s * 6) * 16 + lg * 4;
        #pragma unroll
        for (int mt = 0; mt < 4; ++mt) {
            int n = mt * 16 + lr;             // token (uniform over j)
            if (s == 2) {                     // v^T: 4 channel-rows, col n
                #pragma unroll
                for (int j = 0; j < 4; ++j)
                    smem[LDS_VT + (remBase + j) * 68 + n] = f2s(acc[mt][j] + qb4[j]);
            } else {
                s16x4 pk;
                #pragma unroll
                for (int j = 0; j < 4; ++j) pk[j] = f2s(acc[mt][j] + qb4[j]);
                if (s == 0) { if (n < 49) *reinterpret_cast<s16x4*>(
                                  &smem[LDS_XQ + n * 100 + remBase]) = pk; }
                else        { if (n < 52) *reinterpret_cast<s16x4*>(
                                  &smem[LDS_K  + n * 100 + remBase]) = pk; }
            }
        }
    }

    // ---- mask + gathered-bias loads (af dead; hidden under barrier wait) ----
    float mk[4][4];
    #pragma unroll
    for (int nt = 0; nt < 4; ++nt) {
        int c = nt * 16 + lr;
        #pragma unroll
        for (int j = 0; j < 4; ++j) {
            int n = wid * 16 + lg * 4 + j;
            float m = 0.f;
            if (c < 49 && n < 49)
                m = mask[(size_t)wi * 2401 + n * 49 + c];
            mk[nt][j] = m;
        }
    }
    u16x4 bgv[12];
    #pragma unroll
    for (int i = 0; i < 12; ++i) bgv[i] = biasg[i * 256 + tid];

    __syncthreads();
    // From here: K, VT read-only; XQ/P rows wave-private.

    // ---- per-head attention (wave-private rows; no barriers) ----
    #pragma unroll
    for (int h = 0; h < 3; ++h) {
        bf16x8 aq = *reinterpret_cast<const bf16x8*>(
            &smem[LDS_XQ + (wid * 16 + lr) * 100 + h * 32 + lg * 8]);
        f32x4 sacc[4];
        #pragma unroll
        for (int nt = 0; nt < 4; ++nt) {
            bf16x8 bk = *reinterpret_cast<const bf16x8*>(
                &smem[LDS_K + (nt * 16 + lr) * 100 + h * 32 + lg * 8]);
            sacc[nt] = __builtin_amdgcn_mfma_f32_16x16x32_bf16(aq, bk, (f32x4)0.f, 0, 0, 0);
        }
        float lgt[4][4];
        #pragma unroll
        for (int nt = 0; nt < 4; ++nt) {
            int c = nt * 16 + lr;
            u16x4 bgq = bgv[h * 4 + nt];
            #pragma unroll
            for (int j = 0; j < 4; ++j) {
                float v = -1e30f;
                if (c < 52)
                    v = sacc[nt][j] * SCALE + s2f(bgq[j]) + mk[nt][j];
                lgt[nt][j] = v;
            }
        }
        float pr[4][4];
        #pragma unroll
        for (int j = 0; j < 4; ++j) {
            float m = fmaxf(fmaxf(lgt[0][j], lgt[1][j]), fmaxf(lgt[2][j], lgt[3][j]));
            m = fmaxf(m, __shfl_xor(m, 1));
            m = fmaxf(m, __shfl_xor(m, 2));
            m = fmaxf(m, __shfl_xor(m, 4));
            m = fmaxf(m, __shfl_xor(m, 8));
            float sum = 0.f;
            #pragma unroll
            for (int nt = 0; nt < 4; ++nt) {
                pr[nt][j] = __expf(lgt[nt][j] - m);
                sum += pr[nt][j];
            }
            sum += __shfl_xor(sum, 1);
            sum += __shfl_xor(sum, 2);
            sum += __shfl_xor(sum, 4);
            sum += __shfl_xor(sum, 8);
            float inv = 1.0f / sum;
            #pragma unroll
            for (int nt = 0; nt < 4; ++nt) pr[nt][j] *= inv;
        }
        #pragma unroll
        for (int nt = 0; nt < 4; ++nt)
            #pragma unroll
            for (int j = 0; j < 4; ++j) {
                int prow = wid * 16 + lg * 4 + j;
                if (prow < 49)
                    smem[LDS_P + prow * 68 + nt * 16 + lr] = f2s(pr[nt][j]);
            }

        // O_h = P @ V (K=52 padded to 64; P cols 52-63 exact zeros)
        f32x4 ov[2] = {(f32x4)0.f, (f32x4)0.f};
        #pragma unroll
        for (int ks = 0; ks < 2; ++ks) {
            bf16x8 ap = *reinterpret_cast<const bf16x8*>(
                &smem[LDS_P + (wid * 16 + lr) * 68 + ks * 32 + lg * 8]);
            #pragma unroll
            for (int nt2 = 0; nt2 < 2; ++nt2) {
                bf16x8 bv = *reinterpret_cast<const bf16x8*>(
                    &smem[LDS_VT + (h * 32 + nt2 * 16 + lr) * 68 + ks * 32 + lg * 8]);
                ov[nt2] = __builtin_amdgcn_mfma_f32_16x16x32_bf16(ap, bv, ov[nt2], 0, 0, 0);
            }
        }
        #pragma unroll
        for (int nt2 = 0; nt2 < 2; ++nt2)
            #pragma unroll
            for (int j = 0; j < 4; ++j) {
                int orow = wid * 16 + lg * 4 + j;
                if (orow < 49)
                    smem[LDS_XQ + orow * 100 + h * 32 + nt2 * 16 + lr]
                        = f2s(ov[nt2][j]);
            }
    }

    // ---- projection, SWAPPED: D[ch][tok] -> 6x dwordx4 stores ----
    f32x4 po[6];
    #pragma unroll
    for (int nt = 0; nt < 6; ++nt) po[nt] = (f32x4)0.f;
    #pragma unroll
    for (int ks = 0; ks < 3; ++ks) {
        bf16x8 a = *reinterpret_cast<const bf16x8*>(
            &smem[LDS_XQ + (wid * 16 + lr) * 100 + ks * 32 + lg * 8]);
        #pragma unroll
        for (int nt = 0; nt < 6; ++nt) {
            bf16x8 bp = *reinterpret_cast<const bf16x8*>(
                wp + (nt * 16 + lr) * 96 + ks * 32 + lg * 8);
            // A=W (rows=out channels), B=O (rows=tokens) -> D[ch=lg*4+j][tok=lr]
            po[nt] = __builtin_amdgcn_mfma_f32_16x16x32_bf16(bp, a, po[nt], 0, 0, 0);
        }
    }
    {
        int n = wid * 16 + lr;            // token (uniform over nt, j)
        if (n < 49) {
            float* orow = out + ((size_t)w * 49 + n) * 96;
            #pragma unroll
            for (int nt = 0; nt < 6; ++nt) {
                f32x4 pb4 = *reinterpret_cast<const f32x4*>(proj_b + nt * 16 + lg * 4);
                f32x4 o4;
                #pragma unroll
                for (int j = 0; j < 4; ++j) o4[j] = po[nt][j] + pb4[j];
                *reinterpret_cast<f32x4*>(orow + nt * 16 + lg * 4) = o4;
            }
        }
    }
}

extern "C" void kernel_launch(void* const* d_in, const int* in_sizes, int n_in,
                              void* d_out, int out_size, void* d_ws, size_t ws_size,
                              hipStream_t stream) {
    const float* x          = (const float*)d_in[0];
    const float* mask       = (const float*)d_in[1];
    const float* uk         = (const float*)d_in[2];
    const float* fg         = (const float*)d_in[3];
    const float* bg         = (const float*)d_in[4];
    const float* qkv_w      = (const float*)d_in[5];
    const float* qkv_b      = (const float*)d_in[6];
    const float* proj_w     = (const float*)d_in[7];
    const float* proj_b     = (const float*)d_in[8];
    const float* bias_table = (const float*)d_in[9];
    float* out = (float*)d_out;
    bf16* ws   = (bf16*)d_ws;

    pawsa_prep<<<169, 256, 0, stream>>>(qkv_w, proj_w, bias_table,
                                        uk, fg, bg, qkv_b, proj_b,
                                        ws, out + (size_t)8192 * 49 * 96);
    pawsa_main<<<8192, 256, 0, stream>>>(x, mask, uk, fg, bg,
                                         ws, qkv_b, ws + 27648, proj_b,
                                         (const u16x4*)(ws + 36864), out);
}